// Round 2
// baseline (280.128 us; speedup 1.0000x reference)
//
#include <hip/hip_runtime.h>

// ---------------------------------------------------------------------------
// MusicGenerationV2: two zero-state LSTM cells, fully fused MFMA pipeline.
//   time:  gates = x @ W_ih_t^T + b ; to = sig(o)*tanh(sig(i)*tanh(g))
//   note:  gates = note_in @ W_ih_n^T + b ; y = (sig(o)*tanh(sig(i)*tanh(g)) > 0.5)
// fp16 split-precision (hi+lo, 3 products) = fp32-level accuracy.
// Round 2: barrier-free k1 (all LDS tiles wave-private), Wn read direct from a
// pre-transposed global layout, trans 8->6 per element via prescaled weights +
// bias-in-accumulator, f-gate columns dropped from note GEMM (96->80).
// ---------------------------------------------------------------------------

typedef _Float16 half8  __attribute__((ext_vector_type(8)));
typedef _Float16 half4v __attribute__((ext_vector_type(4)));
typedef float    f32x4  __attribute__((ext_vector_type(4)));

#define T_STEPS 128
#define NBROWS  12288      // 12 notes * 1024 batch
#define ROWS_WG 128        // rows per workgroup (4 waves x 32 rows)
#define NRT     96         // NBROWS / ROWS_WG
#define NCOLS   80         // note gate cols kept: i(24) g(24) o(24) pad(8)

// LDS strides (halves). 16B-aligned rows; strides chosen for low bank conflict.
#define XS_STRIDE 40       // x tile  [128][40], k=0..23 data, 24..31 zero pad
#define TO_STRIDE 88       // to tile [128][88], h=0..63 (88: 4-way -> 2-way reads)

__device__ inline f32x4 mfma16(half8 a, half8 b, f32x4 c) {
  return __builtin_amdgcn_mfma_f32_16x16x32_f16(a, b, c, 0, 0, 0);
}

#define SCALE_SIG  -1.4426950408889634f   // -log2(e): sig(z) = 1/(1+exp2(-log2e*z))
#define SCALE_TANH  2.8853900817779268f   // 2*log2(e): tanh(z)=(E-1)/(E+1), E=exp2(..)

// ---------------------------------------------------------------------------
// Kernel 0: prescale+split time weights; transpose+select+split note weights.
// wsel[c][k], c in [0,192): blk=c/64 -> {i,g,o}; cl=(c%64)&15, ctw=(c%64)>>4,
//   h=cl*4+ctw  (permuted so a lane's 4 gate-cols are 4 consecutive h).
// wnT[t][r][c64]: r in [0,80): rows {i:0-23 -> 0-23, g:48-71 -> 24-47,
//   o:72-95 -> 48-71, zero pad 72-79}; contiguous per t for L2-friendly reads.
// ---------------------------------------------------------------------------
__global__ __launch_bounds__(256) void k0_prep(
    const float* __restrict__ W_ih_t, const float* __restrict__ b_ih_t,
    const float* __restrict__ b_hh_t, const float* __restrict__ W_ih_n,
    _Float16* __restrict__ wsel_hi, _Float16* __restrict__ wsel_lo,
    float* __restrict__ biasp,
    _Float16* __restrict__ wnT_hi, _Float16* __restrict__ wnT_lo)
{
  int id = blockIdx.x * 256 + threadIdx.x;
  if (id < 192 * 32) {
    int c = id >> 5, k = id & 31;
    int blk = c >> 6, ci = c & 63;
    int cl = ci & 15, ctw = ci >> 4;
    int h = cl * 4 + ctw;
    int grow = (blk == 0 ? 0 : (blk == 1 ? 128 : 192)) + h;  // i,g,o rows
    float scale = (blk == 1) ? SCALE_TANH : SCALE_SIG;
    float v = (k < 24) ? W_ih_t[grow * 24 + k] * scale : 0.0f;
    _Float16 hi = (_Float16)v;
    wsel_hi[id] = hi;
    wsel_lo[id] = (_Float16)(v - (float)hi);
    if (k == 0) biasp[c] = (b_ih_t[grow] + b_hh_t[grow]) * scale;
  }
  for (int f = id; f < T_STEPS * NCOLS * 64; f += gridDim.x * 256) {
    int t = f / (NCOLS * 64);
    int rem = f - t * (NCOLS * 64);
    int r = rem >> 6, c = rem & 63;
    float v = 0.0f;
    if (r < 72) {
      int n = (r < 24) ? r : r + 24;   // skip f-gate rows 24..47
      v = W_ih_n[(size_t)n * 8192 + t * 64 + c];
    }
    _Float16 hi = (_Float16)v;
    wnT_hi[f] = hi;
    wnT_lo[f] = (_Float16)(v - (float)hi);
  }
}

// ---------------------------------------------------------------------------
// Kernel 1: fused time-LSTM + note-GEMM partial sums. BARRIER-FREE:
// every LDS tile is wave-private (wave w owns rows [32w,32w+32)).
// grid = NRT * tsplit blocks of 256 threads (4 independent waves).
// ---------------------------------------------------------------------------
__global__ __launch_bounds__(256, 2) void k1_time_note(
    const float* __restrict__ x,
    const _Float16* __restrict__ wsel_hi, const _Float16* __restrict__ wsel_lo,
    const float* __restrict__ biasp,
    const _Float16* __restrict__ wnT_hi, const _Float16* __restrict__ wnT_lo,
    float* __restrict__ partials, int tchunk)
{
  __shared__ _Float16 xs_hi[ROWS_WG * XS_STRIDE];
  __shared__ _Float16 xs_lo[ROWS_WG * XS_STRIDE];
  __shared__ _Float16 tos_hi[ROWS_WG * TO_STRIDE];
  __shared__ _Float16 tos_lo[ROWS_WG * TO_STRIDE];   // total 65536 B -> 2 blk/CU

  const int tid = threadIdx.x;
  const int l   = tid & 63;
  const int w   = tid >> 6;     // wave 0..3, owns rows [w*32, w*32+32)
  const int cl  = l & 15;
  const int kg  = l >> 4;       // 0..3

  const int rt   = blockIdx.x % NRT;
  const int ts   = blockIdx.x / NRT;
  const int row0 = rt * ROWS_WG;
  const int t0   = ts * tchunk;

  // zero the x k-pad (k=24..31) for this wave's own rows (no barrier needed)
  if (l < 32) {
    int row = w * 32 + l;
    half8 z = {0, 0, 0, 0, 0, 0, 0, 0};
    *(half8*)(xs_hi + row * XS_STRIDE + 24) = z;
    *(half8*)(xs_lo + row * XS_STRIDE + 24) = z;
  }

  // W_ih_t fragments (prescaled): register-resident for the whole kernel.
  half8 wth[12], wtl[12];
#pragma unroll
  for (int ct = 0; ct < 12; ++ct) {
    int off = (ct * 16 + cl) * 32 + kg * 8;
    wth[ct] = *(const half8*)(wsel_hi + off);
    wtl[ct] = *(const half8*)(wsel_lo + off);
  }
  float bias[3][4];
#pragma unroll
  for (int blk = 0; blk < 3; ++blk)
#pragma unroll
    for (int ctw = 0; ctw < 4; ++ctw)
      bias[blk][ctw] = biasp[blk * 64 + ctw * 16 + cl];

  f32x4 nacc[2][5];
#pragma unroll
  for (int mt = 0; mt < 2; ++mt)
#pragma unroll
    for (int nt = 0; nt < 5; ++nt)
      nacc[mt][nt] = (f32x4){0.f, 0.f, 0.f, 0.f};

  const int srow = tid >> 1;            // x staging: 2 threads/row, wave-private
  const int sch  = (tid & 1) * 12;

  const float* xp = x + ((size_t)t0 * NBROWS + row0 + srow) * 24 + sch;
  const _Float16* wnh = wnT_hi + (size_t)t0 * NCOLS * 64;
  const _Float16* wnl = wnT_lo + (size_t)t0 * NCOLS * 64;

  for (int tt = 0; tt < tchunk; ++tt) {
    // ---- global x load (next data while previous math drains) ----
    f32x4 xv0 = *(const f32x4*)(xp + 0);
    f32x4 xv1 = *(const f32x4*)(xp + 4);
    f32x4 xv2 = *(const f32x4*)(xp + 8);
    xp += (size_t)NBROWS * 24;

    // ---- stage x (split f32 -> fp16 hi/lo), own rows only ----
    {
      half4v h0, h1, h2, q0, q1, q2;
#pragma unroll
      for (int j = 0; j < 4; ++j) {
        _Float16 a = (_Float16)xv0[j]; h0[j] = a; q0[j] = (_Float16)(xv0[j] - (float)a);
        _Float16 b = (_Float16)xv1[j]; h1[j] = b; q1[j] = (_Float16)(xv1[j] - (float)b);
        _Float16 c = (_Float16)xv2[j]; h2[j] = c; q2[j] = (_Float16)(xv2[j] - (float)c);
      }
      _Float16* dh = xs_hi + srow * XS_STRIDE + sch;
      *(half4v*)(dh + 0) = h0; *(half4v*)(dh + 4) = h1; *(half4v*)(dh + 8) = h2;
      _Float16* dl = xs_lo + srow * XS_STRIDE + sch;
      *(half4v*)(dl + 0) = q0; *(half4v*)(dl + 4) = q1; *(half4v*)(dl + 8) = q2;
    }

    // ---- time MFMA A-frags (own rows; compiler orders via lgkmcnt) ----
    half8 xah[2], xal[2];
#pragma unroll
    for (int mt = 0; mt < 2; ++mt) {
      int off = (w * 32 + mt * 16 + cl) * XS_STRIDE + kg * 8;
      xah[mt] = *(half8*)(xs_hi + off);
      xal[mt] = *(half8*)(xs_lo + off);
    }

    // ---- time MFMA (bias in C-init) + fused activations ----
    half4v pkh[2][4], pkl[2][4];
#pragma unroll
    for (int ctw = 0; ctw < 4; ++ctw) {
      f32x4 g[2][3];
#pragma unroll
      for (int mt = 0; mt < 2; ++mt)
#pragma unroll
        for (int blk = 0; blk < 3; ++blk) {
          int c = blk * 4 + ctw;
          float b = bias[blk][ctw];
          f32x4 a = (f32x4){b, b, b, b};
          a = mfma16(xah[mt], wth[c], a);   // hi*hi
          a = mfma16(xah[mt], wtl[c], a);   // hi*lo
          a = mfma16(xal[mt], wth[c], a);   // lo*hi
          g[mt][blk] = a;
        }
#pragma unroll
      for (int mt = 0; mt < 2; ++mt)
#pragma unroll
        for (int r = 0; r < 4; ++r) {
          // gates already scaled: zi,zo by -log2e; zg by 2log2e
          float Ei = __builtin_amdgcn_exp2f(g[mt][0][r]);   // e^{-i}
          float Eg = __builtin_amdgcn_exp2f(g[mt][1][r]);   // e^{2g}
          float Eo = __builtin_amdgcn_exp2f(g[mt][2][r]);   // e^{-o}
          float d1 = (1.0f + Ei) * (1.0f + Eg);
          float cp = (SCALE_TANH * Eg - SCALE_TANH) * __builtin_amdgcn_rcpf(d1);
          float Ec = __builtin_amdgcn_exp2f(cp);            // e^{2c}
          float d2 = (1.0f + Eo) * (1.0f + Ec);
          float to = (Ec - 1.0f) * __builtin_amdgcn_rcpf(d2);
          _Float16 hh = (_Float16)to;
          pkh[mt][r][ctw] = hh;
          pkl[mt][r][ctw] = (_Float16)(to - (float)hh);
        }
    }
    // write to-tile (own rows): lane owns (rows kg*4+r, h=cl*4..cl*4+3)
#pragma unroll
    for (int mt = 0; mt < 2; ++mt)
#pragma unroll
      for (int r = 0; r < 4; ++r) {
        int row = w * 32 + mt * 16 + kg * 4 + r;
        *(half4v*)(tos_hi + row * TO_STRIDE + cl * 4) = pkh[mt][r];
        *(half4v*)(tos_lo + row * TO_STRIDE + cl * 4) = pkl[mt][r];
      }

    // ---- note MFMA: nacc[32 x 80] += to[32 x 64] * WnT[64 x 80] ----
    half8 tah[2][2], tal[2][2];
#pragma unroll
    for (int mt = 0; mt < 2; ++mt)
#pragma unroll
      for (int kc = 0; kc < 2; ++kc) {
        int off = (w * 32 + mt * 16 + cl) * TO_STRIDE + kc * 32 + kg * 8;
        tah[mt][kc] = *(half8*)(tos_hi + off);
        tal[mt][kc] = *(half8*)(tos_lo + off);
      }
#pragma unroll
    for (int nt = 0; nt < 5; ++nt) {
      const _Float16* bh = wnh + (nt * 16 + cl) * 64 + kg * 8;
      const _Float16* bl = wnl + (nt * 16 + cl) * 64 + kg * 8;
      half8 bh0 = *(const half8*)(bh);
      half8 bh1 = *(const half8*)(bh + 32);
      half8 bl0 = *(const half8*)(bl);
      half8 bl1 = *(const half8*)(bl + 32);
#pragma unroll
      for (int mt = 0; mt < 2; ++mt) {
        nacc[mt][nt] = mfma16(tah[mt][0], bh0, nacc[mt][nt]);
        nacc[mt][nt] = mfma16(tah[mt][0], bl0, nacc[mt][nt]);
        nacc[mt][nt] = mfma16(tal[mt][0], bh0, nacc[mt][nt]);
        nacc[mt][nt] = mfma16(tah[mt][1], bh1, nacc[mt][nt]);
        nacc[mt][nt] = mfma16(tah[mt][1], bl1, nacc[mt][nt]);
        nacc[mt][nt] = mfma16(tal[mt][1], bh1, nacc[mt][nt]);
      }
    }
    wnh += NCOLS * 64;
    wnl += NCOLS * 64;
  }

  // ---- write partial note-gate sums ----
  float* pbase = partials + (size_t)ts * NBROWS * NCOLS;
#pragma unroll
  for (int mt = 0; mt < 2; ++mt)
#pragma unroll
    for (int nt = 0; nt < 5; ++nt)
#pragma unroll
      for (int r = 0; r < 4; ++r) {
        int row = row0 + w * 32 + mt * 16 + kg * 4 + r;
        int col = nt * 16 + cl;
        pbase[(size_t)row * NCOLS + col] = nacc[mt][nt][r];
      }
}

// ---------------------------------------------------------------------------
// Kernel 2: reduce tsplit partials, note activations, threshold.
// ---------------------------------------------------------------------------
__global__ __launch_bounds__(256) void k2_note_out(
    const float* __restrict__ partials,
    const float* __restrict__ b_ih_n, const float* __restrict__ b_hh_n,
    float* __restrict__ out, int tsplit)
{
  int idx = blockIdx.x * 256 + threadIdx.x;
  if (idx >= NBROWS * 24) return;
  int row = idx / 24, jj = idx - row * 24;
  float gi = 0.f, gg = 0.f, go = 0.f;
  for (int p = 0; p < tsplit; ++p) {
    const float* pp = partials + ((size_t)p * NBROWS + row) * NCOLS;
    gi += pp[jj];
    gg += pp[24 + jj];
    go += pp[48 + jj];
  }
  gi += b_ih_n[jj]      + b_hh_n[jj];
  gg += b_ih_n[48 + jj] + b_hh_n[48 + jj];
  go += b_ih_n[72 + jj] + b_hh_n[72 + jj];
  float si = 1.f / (1.f + expf(-gi));
  float so = 1.f / (1.f + expf(-go));
  float v = so * tanhf(si * tanhf(gg));
  out[idx] = (v > 0.5f) ? 1.0f : 0.0f;
}

// ---------------------------------------------------------------------------
extern "C" void kernel_launch(void* const* d_in, const int* in_sizes, int n_in,
                              void* d_out, int out_size, void* d_ws, size_t ws_size,
                              hipStream_t stream)
{
  (void)in_sizes; (void)n_in; (void)out_size;
  const float* x      = (const float*)d_in[0];
  const float* W_ih_t = (const float*)d_in[1];
  const float* b_ih_t = (const float*)d_in[3];
  const float* b_hh_t = (const float*)d_in[4];
  const float* W_ih_n = (const float*)d_in[5];
  const float* b_ih_n = (const float*)d_in[7];
  const float* b_hh_n = (const float*)d_in[8];
  float* out = (float*)d_out;

  char* ws = (char*)d_ws;
  _Float16* wsel_hi = (_Float16*)(ws + 0);                   // 12288 B
  _Float16* wsel_lo = (_Float16*)(ws + 12288);               // 12288 B
  float*    biasp   = (float*)   (ws + 24576);               // 768 B
  _Float16* wnT_hi  = (_Float16*)(ws + 32768);               // 128*80*64*2 = 1310720 B
  _Float16* wnT_lo  = (_Float16*)(ws + 32768 + 1310720);
  float*    partials= (float*)   (ws + 4194304);             // tsplit*12288*80*4

  int tsplit = 8;
  while (tsplit > 1 &&
         4194304ull + (size_t)tsplit * NBROWS * NCOLS * 4 > ws_size)
    tsplit >>= 1;
  int tchunk = T_STEPS / tsplit;

  k0_prep<<<dim3(512), dim3(256), 0, stream>>>(
      W_ih_t, b_ih_t, b_hh_t, W_ih_n, wsel_hi, wsel_lo, biasp, wnT_hi, wnT_lo);

  k1_time_note<<<dim3(NRT * tsplit), dim3(256), 0, stream>>>(
      x, wsel_hi, wsel_lo, biasp, wnT_hi, wnT_lo, partials, tchunk);

  k2_note_out<<<dim3((NBROWS * 24 + 255) / 256), dim3(256), 0, stream>>>(
      partials, b_ih_n, b_hh_n, out, tsplit);
}

// Round 4
// 249.502 us; speedup vs baseline: 1.1227x; 1.1227x over previous
//
#include <hip/hip_runtime.h>

// ---------------------------------------------------------------------------
// MusicGenerationV2: two zero-state LSTM cells, fully fused MFMA pipeline.
//   time:  gates = x @ W_ih_t^T + b ; to = sig(o)*tanh(sig(i)*tanh(g))
//   note:  gates = note_in @ W_ih_n^T + b ; y = (sig(o)*tanh(sig(i)*tanh(g)) > 0.5)
// fp16 split-precision (hi+lo, 3 products) = fp32-level accuracy.
// Round 4 (= round 3 + compile fix): latency-oriented rebuild.
//  - x A-fragments loaded per-lane direct from global, PREFETCHED one t ahead,
//    split to fp16 hi/lo in-register (xs LDS tile deleted).
//  - note weights pre-shuffled by k0 into fragment-ordered [t][nt][kc][p][lane]
//    so k1 stages reg->LDS with contiguous conflict-free 16B/lane accesses,
//    double-buffered one t ahead; ONE __syncthreads per t-step.
//  - tos tile stays (transpose through LDS), stride 72.
// ---------------------------------------------------------------------------

typedef _Float16 half8  __attribute__((ext_vector_type(8)));
typedef _Float16 half4v __attribute__((ext_vector_type(4)));
typedef float    f32x4  __attribute__((ext_vector_type(4)));

#define T_STEPS 128
#define NBROWS  12288      // 12 notes * 1024 batch
#define ROWS_WG 128        // rows per workgroup (4 waves x 32 rows)
#define NRT     96         // NBROWS / ROWS_WG
#define NCOLS   80         // note gate cols kept: i(24) g(24) o(24) pad(8)
#define TO_STRIDE 72       // to tile [128][72] halves
#define WN_T_HALF 10240    // per-t frag-ordered wn halves (5nt*2kc*2p*512)

__device__ inline f32x4 mfma16(half8 a, half8 b, f32x4 c) {
  return __builtin_amdgcn_mfma_f32_16x16x32_f16(a, b, c, 0, 0, 0);
}

#define SCALE_SIG  -1.4426950408889634f   // -log2(e)
#define SCALE_TANH  2.8853900817779268f   // 2*log2(e)

// ---------------------------------------------------------------------------
// Kernel 0: prescale+split time weights; note weights -> fragment order.
// wsel[c][k]: c=blk*64+ctw*16+cl maps gate col h=cl*4+ctw of gate blk {i,g,o}.
// wnF[t*10240 + nt*2048 + kc*1024 + p*512 + l*8 + j]:
//   value = plane_p( Wsel[rcol=nt*16+cl][k=kc*32+kg*8+j] ), l=kg*16+cl,
//   rcol<24 -> W_ih_n row rcol; 24<=rcol<72 -> row rcol+24 (skip f); else 0.
// ---------------------------------------------------------------------------
__global__ __launch_bounds__(256) void k0_prep(
    const float* __restrict__ W_ih_t, const float* __restrict__ b_ih_t,
    const float* __restrict__ b_hh_t, const float* __restrict__ W_ih_n,
    _Float16* __restrict__ wsel_hi, _Float16* __restrict__ wsel_lo,
    float* __restrict__ biasp, _Float16* __restrict__ wnF)
{
  int id = blockIdx.x * 256 + threadIdx.x;
  if (id < 192 * 32) {
    int c = id >> 5, k = id & 31;
    int blk = c >> 6, ci = c & 63;
    int cl = ci & 15, ctw = ci >> 4;
    int h = cl * 4 + ctw;
    int grow = (blk == 0 ? 0 : (blk == 1 ? 128 : 192)) + h;  // i,g,o rows
    float scale = (blk == 1) ? SCALE_TANH : SCALE_SIG;
    float v = (k < 24) ? W_ih_t[grow * 24 + k] * scale : 0.0f;
    _Float16 hi = (_Float16)v;
    wsel_hi[id] = hi;
    wsel_lo[id] = (_Float16)(v - (float)hi);
    if (k == 0) biasp[c] = (b_ih_t[grow] + b_hh_t[grow]) * scale;
  }
  // e indexes (t, nt, kc, l, j); hi at p=0, lo at p=1 (+512 halves)
  for (int e = id; e < T_STEPS * 5120; e += gridDim.x * 256) {
    int t = e / 5120, u = e - t * 5120;
    int nt = u >> 10, u2 = u & 1023;
    int kc = u2 >> 9, u3 = u2 & 511;
    int l = u3 >> 3, j = u3 & 7;
    int cl = l & 15, kg = l >> 4;
    int rcol = nt * 16 + cl;
    int k = kc * 32 + kg * 8 + j;
    float v = 0.0f;
    if (rcol < 72) {
      int n = (rcol < 24) ? rcol : rcol + 24;   // skip f-gate rows 24..47
      v = W_ih_n[(size_t)n * 8192 + t * 64 + k];
    }
    _Float16 hi = (_Float16)v;
    size_t base = (size_t)t * WN_T_HALF + nt * 2048 + kc * 1024 + u3;
    wnF[base]       = hi;
    wnF[base + 512] = (_Float16)(v - (float)hi);
  }
}

// ---------------------------------------------------------------------------
// Kernel 1: fused time-LSTM + note-GEMM partial sums.
// grid = NRT * tsplit blocks of 256 threads (4 waves, 32 rows each).
// ---------------------------------------------------------------------------
__global__ __launch_bounds__(256, 2) void k1_time_note(
    const float* __restrict__ x,
    const _Float16* __restrict__ wsel_hi, const _Float16* __restrict__ wsel_lo,
    const float* __restrict__ biasp, const _Float16* __restrict__ wnF,
    float* __restrict__ partials, int tchunk)
{
  __shared__ _Float16 wns[2][WN_T_HALF];             // 40960 B, dbuf
  __shared__ _Float16 tos_hi[ROWS_WG * TO_STRIDE];   // 18432 B
  __shared__ _Float16 tos_lo[ROWS_WG * TO_STRIDE];   // 18432 B

  const int tid = threadIdx.x;
  const int l   = tid & 63;
  const int w   = tid >> 6;     // wave 0..3, owns rows [w*32, w*32+32)
  const int cl  = l & 15;
  const int kg  = l >> 4;       // 0..3

  const int rt   = blockIdx.x % NRT;
  const int ts   = blockIdx.x / NRT;
  const int row0 = rt * ROWS_WG;
  const int t0   = ts * tchunk;

  // W_ih_t fragments (prescaled): register-resident.
  half8 wth[12], wtl[12];
#pragma unroll
  for (int ct = 0; ct < 12; ++ct) {
    int off = (ct * 16 + cl) * 32 + kg * 8;
    wth[ct] = *(const half8*)(wsel_hi + off);
    wtl[ct] = *(const half8*)(wsel_lo + off);
  }
  float bias[3][4];
#pragma unroll
  for (int blk = 0; blk < 3; ++blk)
#pragma unroll
    for (int ctw = 0; ctw < 4; ++ctw)
      bias[blk][ctw] = biasp[blk * 64 + ctw * 16 + cl];

  f32x4 nacc[2][5];
#pragma unroll
  for (int mt = 0; mt < 2; ++mt)
#pragma unroll
    for (int nt = 0; nt < 5; ++nt)
      nacc[mt][nt] = (f32x4){0.f, 0.f, 0.f, 0.f};

  // per-lane x A-frag source: rows row0 + w*32 + mt*16 + cl, k = kg*8..kg*8+7
  const size_t xrow[2] = {
    (size_t)(row0 + w * 32 + 0  + cl) * 24 + kg * 8,
    (size_t)(row0 + w * 32 + 16 + cl) * 24 + kg * 8 };
  const bool xok = (kg < 3);

  // ---- prologue: load x[t0] and wn[t0]; stage wn[t0] -> wns[0] ----
  float xcur[2][8];
#pragma unroll
  for (int mt = 0; mt < 2; ++mt) {
    f32x4 a = {0,0,0,0}, b = {0,0,0,0};
    if (xok) {
      const float* g = x + (size_t)t0 * NBROWS * 24 + xrow[mt];
      a = *(const f32x4*)g;
      b = *(const f32x4*)(g + 4);
    }
#pragma unroll
    for (int q = 0; q < 4; ++q) { xcur[mt][q] = a[q]; xcur[mt][4 + q] = b[q]; }
  }
  {
    const _Float16* src = wnF + (size_t)t0 * WN_T_HALF + w * 512 + l * 8;
    _Float16* dst = &wns[0][w * 512 + l * 8];
#pragma unroll
    for (int i = 0; i < 5; ++i)
      *(half8*)(dst + i * 2048) = *(const half8*)(src + i * 2048);
  }
  __syncthreads();

  for (int tt = 0; tt < tchunk; ++tt) {
    const int rb = tt & 1, wb = rb ^ 1;
    int tg = t0 + tt + 1; if (tg > T_STEPS - 1) tg = T_STEPS - 1;

    // ---- 1. issue wn[t+1] global loads (consumed at iteration bottom) ----
    half8 wnext[5];
    {
      const _Float16* src = wnF + (size_t)tg * WN_T_HALF + w * 512 + l * 8;
#pragma unroll
      for (int i = 0; i < 5; ++i) wnext[i] = *(const half8*)(src + i * 2048);
    }

    // ---- 2. split x[t] (from prefetch regs) -> fp16 hi/lo A-frags ----
    half8 xah[2], xal[2];
#pragma unroll
    for (int mt = 0; mt < 2; ++mt) {
#pragma unroll
      for (int q = 0; q < 8; ++q) {
        _Float16 h = (_Float16)xcur[mt][q];
        xah[mt][q] = h;
        xal[mt][q] = (_Float16)(xcur[mt][q] - (float)h);
      }
    }

    // ---- 3. time MFMA (bias in C-init) ----
    f32x4 g[4][2][3];   // [ctw][mt][blk]
#pragma unroll
    for (int ctw = 0; ctw < 4; ++ctw)
#pragma unroll
      for (int mt = 0; mt < 2; ++mt)
#pragma unroll
        for (int blk = 0; blk < 3; ++blk) {
          int c = blk * 4 + ctw;
          float b = bias[blk][ctw];
          f32x4 a = (f32x4){b, b, b, b};
          a = mfma16(xah[mt], wth[c], a);   // hi*hi
          a = mfma16(xah[mt], wtl[c], a);   // hi*lo
          a = mfma16(xal[mt], wth[c], a);   // lo*hi
          g[ctw][mt][blk] = a;
        }

    // ---- 4. issue x[t+1] loads (covered by trans + note-MFMA) ----
    float xnxt[2][8];
#pragma unroll
    for (int mt = 0; mt < 2; ++mt) {
      f32x4 a = {0,0,0,0}, b = {0,0,0,0};
      if (xok) {
        const float* gp = x + (size_t)tg * NBROWS * 24 + xrow[mt];
        a = *(const f32x4*)gp;
        b = *(const f32x4*)(gp + 4);
      }
#pragma unroll
      for (int q = 0; q < 4; ++q) { xnxt[mt][q] = a[q]; xnxt[mt][4 + q] = b[q]; }
    }

    // ---- 5. activations (6 trans/elem) + split to fp16 hi/lo ----
    half4v pkh[2][4], pkl[2][4];
#pragma unroll
    for (int ctw = 0; ctw < 4; ++ctw)
#pragma unroll
      for (int mt = 0; mt < 2; ++mt)
#pragma unroll
        for (int r = 0; r < 4; ++r) {
          float Ei = __builtin_amdgcn_exp2f(g[ctw][mt][0][r]);  // e^{-i}
          float Eg = __builtin_amdgcn_exp2f(g[ctw][mt][1][r]);  // e^{2g}
          float Eo = __builtin_amdgcn_exp2f(g[ctw][mt][2][r]);  // e^{-o}
          float d1 = (1.0f + Ei) * (1.0f + Eg);
          float cp = (SCALE_TANH * Eg - SCALE_TANH) * __builtin_amdgcn_rcpf(d1);
          float Ec = __builtin_amdgcn_exp2f(cp);                // e^{2c}
          float d2 = (1.0f + Eo) * (1.0f + Ec);
          float to = (Ec - 1.0f) * __builtin_amdgcn_rcpf(d2);
          _Float16 hh = (_Float16)to;
          pkh[mt][r][ctw] = hh;
          pkl[mt][r][ctw] = (_Float16)(to - (float)hh);
        }

    // ---- 6. tos write (wave-private rows) ----
#pragma unroll
    for (int mt = 0; mt < 2; ++mt)
#pragma unroll
      for (int r = 0; r < 4; ++r) {
        int row = w * 32 + mt * 16 + kg * 4 + r;
        *(half4v*)(tos_hi + row * TO_STRIDE + cl * 4) = pkh[mt][r];
        *(half4v*)(tos_lo + row * TO_STRIDE + cl * 4) = pkl[mt][r];
      }

    // ---- 7. note MFMA: nacc[32 x 80] += to[32 x 64] * WnT[64 x 80] ----
    half8 tah[2][2], tal[2][2];
#pragma unroll
    for (int mt = 0; mt < 2; ++mt)
#pragma unroll
      for (int kc = 0; kc < 2; ++kc) {
        int off = (w * 32 + mt * 16 + cl) * TO_STRIDE + kc * 32 + kg * 8;
        tah[mt][kc] = *(half8*)(tos_hi + off);
        tal[mt][kc] = *(half8*)(tos_lo + off);
      }
#pragma unroll
    for (int nt = 0; nt < 5; ++nt) {
#pragma unroll
      for (int kc = 0; kc < 2; ++kc) {
        const _Float16* bb = &wns[rb][nt * 2048 + kc * 1024 + l * 8];
        half8 bh = *(const half8*)(bb);         // plane hi
        half8 bl = *(const half8*)(bb + 512);   // plane lo
#pragma unroll
        for (int mt = 0; mt < 2; ++mt) {
          nacc[mt][nt] = mfma16(tah[mt][kc], bh, nacc[mt][nt]);
          nacc[mt][nt] = mfma16(tah[mt][kc], bl, nacc[mt][nt]);
          nacc[mt][nt] = mfma16(tal[mt][kc], bh, nacc[mt][nt]);
        }
      }
    }

    // ---- 8. stage wn[t+1] into the other buffer; one barrier per t ----
    {
      _Float16* dst = &wns[wb][w * 512 + l * 8];
#pragma unroll
      for (int i = 0; i < 5; ++i) *(half8*)(dst + i * 2048) = wnext[i];
    }
    __syncthreads();

    // ---- 9. rotate x prefetch ----
#pragma unroll
    for (int mt = 0; mt < 2; ++mt)
#pragma unroll
      for (int q = 0; q < 8; ++q) xcur[mt][q] = xnxt[mt][q];
  }

  // ---- write partial note-gate sums ----
  float* pbase = partials + (size_t)ts * NBROWS * NCOLS;
#pragma unroll
  for (int mt = 0; mt < 2; ++mt)
#pragma unroll
    for (int nt = 0; nt < 5; ++nt)
#pragma unroll
      for (int r = 0; r < 4; ++r) {
        int row = row0 + w * 32 + mt * 16 + kg * 4 + r;
        int col = nt * 16 + cl;
        pbase[(size_t)row * NCOLS + col] = nacc[mt][nt][r];
      }
}

// ---------------------------------------------------------------------------
// Kernel 2: reduce tsplit partials, note activations, threshold.
// ---------------------------------------------------------------------------
__global__ __launch_bounds__(256) void k2_note_out(
    const float* __restrict__ partials,
    const float* __restrict__ b_ih_n, const float* __restrict__ b_hh_n,
    float* __restrict__ out, int tsplit)
{
  int idx = blockIdx.x * 256 + threadIdx.x;
  if (idx >= NBROWS * 24) return;
  int row = idx / 24, jj = idx - row * 24;
  float gi = 0.f, gg = 0.f, go = 0.f;
  for (int p = 0; p < tsplit; ++p) {
    const float* pp = partials + ((size_t)p * NBROWS + row) * NCOLS;
    gi += pp[jj];
    gg += pp[24 + jj];
    go += pp[48 + jj];
  }
  gi += b_ih_n[jj]      + b_hh_n[jj];
  gg += b_ih_n[48 + jj] + b_hh_n[48 + jj];
  go += b_ih_n[72 + jj] + b_hh_n[72 + jj];
  float si = 1.f / (1.f + expf(-gi));
  float so = 1.f / (1.f + expf(-go));
  float v = so * tanhf(si * tanhf(gg));
  out[idx] = (v > 0.5f) ? 1.0f : 0.0f;
}

// ---------------------------------------------------------------------------
extern "C" void kernel_launch(void* const* d_in, const int* in_sizes, int n_in,
                              void* d_out, int out_size, void* d_ws, size_t ws_size,
                              hipStream_t stream)
{
  (void)in_sizes; (void)n_in; (void)out_size;
  const float* x      = (const float*)d_in[0];
  const float* W_ih_t = (const float*)d_in[1];
  const float* b_ih_t = (const float*)d_in[3];
  const float* b_hh_t = (const float*)d_in[4];
  const float* W_ih_n = (const float*)d_in[5];
  const float* b_ih_n = (const float*)d_in[7];
  const float* b_hh_n = (const float*)d_in[8];
  float* out = (float*)d_out;

  char* ws = (char*)d_ws;
  _Float16* wsel_hi = (_Float16*)(ws + 0);                   // 12288 B
  _Float16* wsel_lo = (_Float16*)(ws + 12288);               // 12288 B
  float*    biasp   = (float*)   (ws + 24576);               // 768 B
  _Float16* wnF     = (_Float16*)(ws + 32768);               // 128*10240*2 = 2621440 B
  float*    partials= (float*)   (ws + 4194304);             // tsplit*12288*80*4

  int tsplit = 8;
  while (tsplit > 1 &&
         4194304ull + (size_t)tsplit * NBROWS * NCOLS * 4 > ws_size)
    tsplit >>= 1;
  int tchunk = T_STEPS / tsplit;

  k0_prep<<<dim3(512), dim3(256), 0, stream>>>(
      W_ih_t, b_ih_t, b_hh_t, W_ih_n, wsel_hi, wsel_lo, biasp, wnF);

  k1_time_note<<<dim3(NRT * tsplit), dim3(256), 0, stream>>>(
      x, wsel_hi, wsel_lo, biasp, wnF, partials, tchunk);

  k2_note_out<<<dim3((NBROWS * 24 + 255) / 256), dim3(256), 0, stream>>>(
      partials, b_ih_n, b_hh_n, out, tsplit);
}

// Round 5
// 218.143 us; speedup vs baseline: 1.2841x; 1.1438x over previous
//
#include <hip/hip_runtime.h>

// ---------------------------------------------------------------------------
// MusicGenerationV2: two zero-state LSTM cells, fully fused MFMA pipeline.
//   time:  gates = x @ W_ih_t^T + b ; to = sig(o)*tanh(sig(i)*tanh(g))
//   note:  gates = note_in @ W_ih_n^T + b ; y = (sig(o)*tanh(sig(i)*tanh(g)) > 0.5)
// fp16 split-precision (hi+lo, 3 products) = fp32-level accuracy.
// Round 5: register-pressure fix.
//  - amdgpu_waves_per_eu(2,2): LDS already caps at 2 blocks/CU; stop the
//    allocator from spilling loop-invariant weights to scratch (round 4:
//    +290 MB FETCH = spill reloads every iteration).
//  - wn staging via global_load_lds (width 16): frees the 40-VGPR wnext buf,
//    no reg round trip; barrier's vmcnt drain is the only wait.
//  - per-ctw activation fusion: g[2][3] transient (24 VGPR) instead of
//    g[4][2][3] (96 VGPR).
// ---------------------------------------------------------------------------

typedef _Float16 half8  __attribute__((ext_vector_type(8)));
typedef _Float16 half4v __attribute__((ext_vector_type(4)));
typedef float    f32x4  __attribute__((ext_vector_type(4)));

#define T_STEPS 128
#define NBROWS  12288      // 12 notes * 1024 batch
#define ROWS_WG 128        // rows per workgroup (4 waves x 32 rows)
#define NRT     96         // NBROWS / ROWS_WG
#define NCOLS   80         // note gate cols kept: i(24) g(24) o(24) pad(8)
#define TO_STRIDE 72       // to tile [128][72] halves
#define WN_T_HALF 10240    // per-t frag-ordered wn halves (5nt*2kc*2p*512)

__device__ inline f32x4 mfma16(half8 a, half8 b, f32x4 c) {
  return __builtin_amdgcn_mfma_f32_16x16x32_f16(a, b, c, 0, 0, 0);
}

__device__ inline void gload_lds16(const _Float16* gsrc, _Float16* ldst) {
  __builtin_amdgcn_global_load_lds(
      (const __attribute__((address_space(1))) void*)gsrc,
      (__attribute__((address_space(3))) void*)ldst, 16, 0, 0);
}

#define SCALE_SIG  -1.4426950408889634f   // -log2(e)
#define SCALE_TANH  2.8853900817779268f   // 2*log2(e)

// ---------------------------------------------------------------------------
// Kernel 0: prescale+split time weights; note weights -> fragment order.
// wsel[c][k]: c=blk*64+ctw*16+cl maps gate col h=cl*4+ctw of gate blk {i,g,o}.
// wnF[t*10240 + nt*2048 + kc*1024 + p*512 + l*8 + j]:
//   value = plane_p( Wsel[rcol=nt*16+cl][k=kc*32+kg*8+j] ), l=kg*16+cl,
//   rcol<24 -> W_ih_n row rcol; 24<=rcol<72 -> row rcol+24 (skip f); else 0.
// ---------------------------------------------------------------------------
__global__ __launch_bounds__(256) void k0_prep(
    const float* __restrict__ W_ih_t, const float* __restrict__ b_ih_t,
    const float* __restrict__ b_hh_t, const float* __restrict__ W_ih_n,
    _Float16* __restrict__ wsel_hi, _Float16* __restrict__ wsel_lo,
    float* __restrict__ biasp, _Float16* __restrict__ wnF)
{
  int id = blockIdx.x * 256 + threadIdx.x;
  if (id < 192 * 32) {
    int c = id >> 5, k = id & 31;
    int blk = c >> 6, ci = c & 63;
    int cl = ci & 15, ctw = ci >> 4;
    int h = cl * 4 + ctw;
    int grow = (blk == 0 ? 0 : (blk == 1 ? 128 : 192)) + h;  // i,g,o rows
    float scale = (blk == 1) ? SCALE_TANH : SCALE_SIG;
    float v = (k < 24) ? W_ih_t[grow * 24 + k] * scale : 0.0f;
    _Float16 hi = (_Float16)v;
    wsel_hi[id] = hi;
    wsel_lo[id] = (_Float16)(v - (float)hi);
    if (k == 0) biasp[c] = (b_ih_t[grow] + b_hh_t[grow]) * scale;
  }
  // e indexes (t, nt, kc, l, j); hi at p=0, lo at p=1 (+512 halves)
  for (int e = id; e < T_STEPS * 5120; e += gridDim.x * 256) {
    int t = e / 5120, u = e - t * 5120;
    int nt = u >> 10, u2 = u & 1023;
    int kc = u2 >> 9, u3 = u2 & 511;
    int l = u3 >> 3, j = u3 & 7;
    int cl = l & 15, kg = l >> 4;
    int rcol = nt * 16 + cl;
    int k = kc * 32 + kg * 8 + j;
    float v = 0.0f;
    if (rcol < 72) {
      int n = (rcol < 24) ? rcol : rcol + 24;   // skip f-gate rows 24..47
      v = W_ih_n[(size_t)n * 8192 + t * 64 + k];
    }
    _Float16 hi = (_Float16)v;
    size_t base = (size_t)t * WN_T_HALF + nt * 2048 + kc * 1024 + u3;
    wnF[base]       = hi;
    wnF[base + 512] = (_Float16)(v - (float)hi);
  }
}

// ---------------------------------------------------------------------------
// Kernel 1: fused time-LSTM + note-GEMM partial sums.
// grid = NRT * tsplit blocks of 256 threads (4 waves, 32 rows each).
// ---------------------------------------------------------------------------
__global__ __launch_bounds__(256)
__attribute__((amdgpu_waves_per_eu(2, 2)))
void k1_time_note(
    const float* __restrict__ x,
    const _Float16* __restrict__ wsel_hi, const _Float16* __restrict__ wsel_lo,
    const float* __restrict__ biasp, const _Float16* __restrict__ wnF,
    float* __restrict__ partials, int tchunk)
{
  __shared__ _Float16 wns[2][WN_T_HALF];             // 40960 B, dbuf
  __shared__ _Float16 tos_hi[ROWS_WG * TO_STRIDE];   // 18432 B
  __shared__ _Float16 tos_lo[ROWS_WG * TO_STRIDE];   // 18432 B -> 77824 total

  const int tid = threadIdx.x;
  const int l   = tid & 63;
  const int w   = tid >> 6;     // wave 0..3, owns rows [w*32, w*32+32)
  const int cl  = l & 15;
  const int kg  = l >> 4;       // 0..3

  const int rt   = blockIdx.x % NRT;
  const int ts   = blockIdx.x / NRT;
  const int row0 = rt * ROWS_WG;
  const int t0   = ts * tchunk;

  // W_ih_t fragments (prescaled): register-resident.
  half8 wth[12], wtl[12];
#pragma unroll
  for (int ct = 0; ct < 12; ++ct) {
    int off = (ct * 16 + cl) * 32 + kg * 8;
    wth[ct] = *(const half8*)(wsel_hi + off);
    wtl[ct] = *(const half8*)(wsel_lo + off);
  }
  float bias[3][4];
#pragma unroll
  for (int blk = 0; blk < 3; ++blk)
#pragma unroll
    for (int ctw = 0; ctw < 4; ++ctw)
      bias[blk][ctw] = biasp[blk * 64 + ctw * 16 + cl];

  f32x4 nacc[2][5];
#pragma unroll
  for (int mt = 0; mt < 2; ++mt)
#pragma unroll
    for (int nt = 0; nt < 5; ++nt)
      nacc[mt][nt] = (f32x4){0.f, 0.f, 0.f, 0.f};

  // per-lane x A-frag source: rows row0 + w*32 + mt*16 + cl, k = kg*8..kg*8+7
  const size_t xrow[2] = {
    (size_t)(row0 + w * 32 + 0  + cl) * 24 + kg * 8,
    (size_t)(row0 + w * 32 + 16 + cl) * 24 + kg * 8 };
  const bool xok = (kg < 3);

  // ---- prologue: load x[t0] to regs; wn[t0] -> wns[0] via global_load_lds ----
  float xcur[2][8];
#pragma unroll
  for (int mt = 0; mt < 2; ++mt) {
    f32x4 a = {0,0,0,0}, b = {0,0,0,0};
    if (xok) {
      const float* g = x + (size_t)t0 * NBROWS * 24 + xrow[mt];
      a = *(const f32x4*)g;
      b = *(const f32x4*)(g + 4);
    }
#pragma unroll
    for (int q = 0; q < 4; ++q) { xcur[mt][q] = a[q]; xcur[mt][4 + q] = b[q]; }
  }
  {
    const _Float16* src = wnF + (size_t)t0 * WN_T_HALF + w * 512 + l * 8;
    _Float16* dst = &wns[0][w * 512];    // wave-uniform; HW adds lane*16B
#pragma unroll
    for (int i = 0; i < 5; ++i)
      gload_lds16(src + i * 2048, dst + i * 2048);
  }
  __syncthreads();

  for (int tt = 0; tt < tchunk; ++tt) {
    const int rb = tt & 1, wb = rb ^ 1;
    int tg = t0 + tt + 1; if (tg > T_STEPS - 1) tg = T_STEPS - 1;

    // ---- 1. issue wn[t+1] -> wns[wb] (no VGPR round trip) ----
    {
      const _Float16* src = wnF + (size_t)tg * WN_T_HALF + w * 512 + l * 8;
      _Float16* dst = &wns[wb][w * 512];
#pragma unroll
      for (int i = 0; i < 5; ++i)
        gload_lds16(src + i * 2048, dst + i * 2048);
    }

    // ---- 2. split x[t] (prefetch regs) -> fp16 hi/lo A-frags ----
    half8 xah[2], xal[2];
#pragma unroll
    for (int mt = 0; mt < 2; ++mt) {
#pragma unroll
      for (int q = 0; q < 8; ++q) {
        _Float16 h = (_Float16)xcur[mt][q];
        xah[mt][q] = h;
        xal[mt][q] = (_Float16)(xcur[mt][q] - (float)h);
      }
    }

    // ---- 3. time MFMA + fused activations, per ctw (small live set) ----
    half4v pkh[2][4], pkl[2][4];
#pragma unroll
    for (int ctw = 0; ctw < 4; ++ctw) {
      f32x4 g[2][3];
#pragma unroll
      for (int mt = 0; mt < 2; ++mt)
#pragma unroll
        for (int blk = 0; blk < 3; ++blk) {
          int c = blk * 4 + ctw;
          float b = bias[blk][ctw];
          f32x4 a = (f32x4){b, b, b, b};
          a = mfma16(xah[mt], wth[c], a);   // hi*hi
          a = mfma16(xah[mt], wtl[c], a);   // hi*lo
          a = mfma16(xal[mt], wth[c], a);   // lo*hi
          g[mt][blk] = a;
        }
#pragma unroll
      for (int mt = 0; mt < 2; ++mt)
#pragma unroll
        for (int r = 0; r < 4; ++r) {
          float Ei = __builtin_amdgcn_exp2f(g[mt][0][r]);   // e^{-i}
          float Eg = __builtin_amdgcn_exp2f(g[mt][1][r]);   // e^{2g}
          float Eo = __builtin_amdgcn_exp2f(g[mt][2][r]);   // e^{-o}
          float d1 = (1.0f + Ei) * (1.0f + Eg);
          float cp = (SCALE_TANH * Eg - SCALE_TANH) * __builtin_amdgcn_rcpf(d1);
          float Ec = __builtin_amdgcn_exp2f(cp);            // e^{2c}
          float d2 = (1.0f + Eo) * (1.0f + Ec);
          float to = (Ec - 1.0f) * __builtin_amdgcn_rcpf(d2);
          _Float16 hh = (_Float16)to;
          pkh[mt][r][ctw] = hh;
          pkl[mt][r][ctw] = (_Float16)(to - (float)hh);
        }
    }

    // ---- 4. issue x[t+1] loads (covered by tos + note-MFMA) ----
    float xnxt[2][8];
#pragma unroll
    for (int mt = 0; mt < 2; ++mt) {
      f32x4 a = {0,0,0,0}, b = {0,0,0,0};
      if (xok) {
        const float* gp = x + (size_t)tg * NBROWS * 24 + xrow[mt];
        a = *(const f32x4*)gp;
        b = *(const f32x4*)(gp + 4);
      }
#pragma unroll
      for (int q = 0; q < 4; ++q) { xnxt[mt][q] = a[q]; xnxt[mt][4 + q] = b[q]; }
    }

    // ---- 5. tos write (wave-private rows) ----
#pragma unroll
    for (int mt = 0; mt < 2; ++mt)
#pragma unroll
      for (int r = 0; r < 4; ++r) {
        int row = w * 32 + mt * 16 + kg * 4 + r;
        *(half4v*)(tos_hi + row * TO_STRIDE + cl * 4) = pkh[mt][r];
        *(half4v*)(tos_lo + row * TO_STRIDE + cl * 4) = pkl[mt][r];
      }

    // ---- 6. note MFMA: nacc[32 x 80] += to[32 x 64] * WnT[64 x 80] ----
    half8 tah[2][2], tal[2][2];
#pragma unroll
    for (int mt = 0; mt < 2; ++mt)
#pragma unroll
      for (int kc = 0; kc < 2; ++kc) {
        int off = (w * 32 + mt * 16 + cl) * TO_STRIDE + kc * 32 + kg * 8;
        tah[mt][kc] = *(half8*)(tos_hi + off);
        tal[mt][kc] = *(half8*)(tos_lo + off);
      }
#pragma unroll
    for (int nt = 0; nt < 5; ++nt) {
#pragma unroll
      for (int kc = 0; kc < 2; ++kc) {
        const _Float16* bb = &wns[rb][nt * 2048 + kc * 1024 + l * 8];
        half8 bh = *(const half8*)(bb);         // plane hi
        half8 bl = *(const half8*)(bb + 512);   // plane lo
#pragma unroll
        for (int mt = 0; mt < 2; ++mt) {
          nacc[mt][nt] = mfma16(tah[mt][kc], bh, nacc[mt][nt]);
          nacc[mt][nt] = mfma16(tah[mt][kc], bl, nacc[mt][nt]);
          nacc[mt][nt] = mfma16(tal[mt][kc], bh, nacc[mt][nt]);
        }
      }
    }

    // ---- 7. barrier: drains wn[t+1] gload_lds (vmcnt) + syncs buffers ----
    __syncthreads();

    // ---- 8. rotate x prefetch ----
#pragma unroll
    for (int mt = 0; mt < 2; ++mt)
#pragma unroll
      for (int q = 0; q < 8; ++q) xcur[mt][q] = xnxt[mt][q];
  }

  // ---- write partial note-gate sums ----
  float* pbase = partials + (size_t)ts * NBROWS * NCOLS;
#pragma unroll
  for (int mt = 0; mt < 2; ++mt)
#pragma unroll
    for (int nt = 0; nt < 5; ++nt)
#pragma unroll
      for (int r = 0; r < 4; ++r) {
        int row = row0 + w * 32 + mt * 16 + kg * 4 + r;
        int col = nt * 16 + cl;
        pbase[(size_t)row * NCOLS + col] = nacc[mt][nt][r];
      }
}

// ---------------------------------------------------------------------------
// Kernel 2: reduce tsplit partials, note activations, threshold.
// ---------------------------------------------------------------------------
__global__ __launch_bounds__(256) void k2_note_out(
    const float* __restrict__ partials,
    const float* __restrict__ b_ih_n, const float* __restrict__ b_hh_n,
    float* __restrict__ out, int tsplit)
{
  int idx = blockIdx.x * 256 + threadIdx.x;
  if (idx >= NBROWS * 24) return;
  int row = idx / 24, jj = idx - row * 24;
  float gi = 0.f, gg = 0.f, go = 0.f;
  for (int p = 0; p < tsplit; ++p) {
    const float* pp = partials + ((size_t)p * NBROWS + row) * NCOLS;
    gi += pp[jj];
    gg += pp[24 + jj];
    go += pp[48 + jj];
  }
  gi += b_ih_n[jj]      + b_hh_n[jj];
  gg += b_ih_n[48 + jj] + b_hh_n[48 + jj];
  go += b_ih_n[72 + jj] + b_hh_n[72 + jj];
  float si = 1.f / (1.f + expf(-gi));
  float so = 1.f / (1.f + expf(-go));
  float v = so * tanhf(si * tanhf(gg));
  out[idx] = (v > 0.5f) ? 1.0f : 0.0f;
}

// ---------------------------------------------------------------------------
extern "C" void kernel_launch(void* const* d_in, const int* in_sizes, int n_in,
                              void* d_out, int out_size, void* d_ws, size_t ws_size,
                              hipStream_t stream)
{
  (void)in_sizes; (void)n_in; (void)out_size;
  const float* x      = (const float*)d_in[0];
  const float* W_ih_t = (const float*)d_in[1];
  const float* b_ih_t = (const float*)d_in[3];
  const float* b_hh_t = (const float*)d_in[4];
  const float* W_ih_n = (const float*)d_in[5];
  const float* b_ih_n = (const float*)d_in[7];
  const float* b_hh_n = (const float*)d_in[8];
  float* out = (float*)d_out;

  char* ws = (char*)d_ws;
  _Float16* wsel_hi = (_Float16*)(ws + 0);                   // 12288 B
  _Float16* wsel_lo = (_Float16*)(ws + 12288);               // 12288 B
  float*    biasp   = (float*)   (ws + 24576);               // 768 B
  _Float16* wnF     = (_Float16*)(ws + 32768);               // 128*10240*2 = 2621440 B
  float*    partials= (float*)   (ws + 4194304);             // tsplit*12288*80*4

  int tsplit = 8;
  while (tsplit > 1 &&
         4194304ull + (size_t)tsplit * NBROWS * NCOLS * 4 > ws_size)
    tsplit >>= 1;
  int tchunk = T_STEPS / tsplit;

  k0_prep<<<dim3(512), dim3(256), 0, stream>>>(
      W_ih_t, b_ih_t, b_hh_t, W_ih_n, wsel_hi, wsel_lo, biasp, wnF);

  k1_time_note<<<dim3(NRT * tsplit), dim3(256), 0, stream>>>(
      x, wsel_hi, wsel_lo, biasp, wnF, partials, tchunk);

  k2_note_out<<<dim3((NBROWS * 24 + 255) / 256), dim3(256), 0, stream>>>(
      partials, b_ih_n, b_hh_n, out, tsplit);
}

// Round 6
// 217.404 us; speedup vs baseline: 1.2885x; 1.0034x over previous
//
#include <hip/hip_runtime.h>

// ---------------------------------------------------------------------------
// MusicGenerationV2: two zero-state LSTM cells, fully fused MFMA pipeline.
//   time:  gates = x @ W_ih_t^T + b ; to = sig(o)*tanh(sig(i)*tanh(g))
//   note:  gates = note_in @ W_ih_n^T + b ; y = (sig(o)*tanh(sig(i)*tanh(g)) > 0.5)
// fp16 split-precision (hi+lo, 3 products) = fp32-level accuracy.
// Round 6: occupancy/VGPR truth-telling via __launch_bounds__(256, 2).
//  Round 5's amdgpu_waves_per_eu attribute was ignored (VGPR_Count stayed 128
//  -> ~145 MB spill reloads + ~47 MB spill stores per dispatch). The 2nd
//  launch_bounds arg (min waves/EU = 2) raises the VGPR budget to 256, which
//  fits the whole live set (wth/wtl 96 + nacc 40 + bias 12 + prefetch ~64).
// ---------------------------------------------------------------------------

typedef _Float16 half8  __attribute__((ext_vector_type(8)));
typedef _Float16 half4v __attribute__((ext_vector_type(4)));
typedef float    f32x4  __attribute__((ext_vector_type(4)));

#define T_STEPS 128
#define NBROWS  12288      // 12 notes * 1024 batch
#define ROWS_WG 128        // rows per workgroup (4 waves x 32 rows)
#define NRT     96         // NBROWS / ROWS_WG
#define NCOLS   80         // note gate cols kept: i(24) g(24) o(24) pad(8)
#define TO_STRIDE 72       // to tile [128][72] halves
#define WN_T_HALF 10240    // per-t frag-ordered wn halves (5nt*2kc*2p*512)

__device__ inline f32x4 mfma16(half8 a, half8 b, f32x4 c) {
  return __builtin_amdgcn_mfma_f32_16x16x32_f16(a, b, c, 0, 0, 0);
}

__device__ inline void gload_lds16(const _Float16* gsrc, _Float16* ldst) {
  __builtin_amdgcn_global_load_lds(
      (const __attribute__((address_space(1))) void*)gsrc,
      (__attribute__((address_space(3))) void*)ldst, 16, 0, 0);
}

#define SCALE_SIG  -1.4426950408889634f   // -log2(e)
#define SCALE_TANH  2.8853900817779268f   // 2*log2(e)

// ---------------------------------------------------------------------------
// Kernel 0: prescale+split time weights; note weights -> fragment order.
// wsel[c][k]: c=blk*64+ctw*16+cl maps gate col h=cl*4+ctw of gate blk {i,g,o}.
// wnF[t*10240 + nt*2048 + kc*1024 + p*512 + l*8 + j]:
//   value = plane_p( Wsel[rcol=nt*16+cl][k=kc*32+kg*8+j] ), l=kg*16+cl,
//   rcol<24 -> W_ih_n row rcol; 24<=rcol<72 -> row rcol+24 (skip f); else 0.
// ---------------------------------------------------------------------------
__global__ __launch_bounds__(256) void k0_prep(
    const float* __restrict__ W_ih_t, const float* __restrict__ b_ih_t,
    const float* __restrict__ b_hh_t, const float* __restrict__ W_ih_n,
    _Float16* __restrict__ wsel_hi, _Float16* __restrict__ wsel_lo,
    float* __restrict__ biasp, _Float16* __restrict__ wnF)
{
  int id = blockIdx.x * 256 + threadIdx.x;
  if (id < 192 * 32) {
    int c = id >> 5, k = id & 31;
    int blk = c >> 6, ci = c & 63;
    int cl = ci & 15, ctw = ci >> 4;
    int h = cl * 4 + ctw;
    int grow = (blk == 0 ? 0 : (blk == 1 ? 128 : 192)) + h;  // i,g,o rows
    float scale = (blk == 1) ? SCALE_TANH : SCALE_SIG;
    float v = (k < 24) ? W_ih_t[grow * 24 + k] * scale : 0.0f;
    _Float16 hi = (_Float16)v;
    wsel_hi[id] = hi;
    wsel_lo[id] = (_Float16)(v - (float)hi);
    if (k == 0) biasp[c] = (b_ih_t[grow] + b_hh_t[grow]) * scale;
  }
  // e indexes (t, nt, kc, l, j); hi at p=0, lo at p=1 (+512 halves)
  for (int e = id; e < T_STEPS * 5120; e += gridDim.x * 256) {
    int t = e / 5120, u = e - t * 5120;
    int nt = u >> 10, u2 = u & 1023;
    int kc = u2 >> 9, u3 = u2 & 511;
    int l = u3 >> 3, j = u3 & 7;
    int cl = l & 15, kg = l >> 4;
    int rcol = nt * 16 + cl;
    int k = kc * 32 + kg * 8 + j;
    float v = 0.0f;
    if (rcol < 72) {
      int n = (rcol < 24) ? rcol : rcol + 24;   // skip f-gate rows 24..47
      v = W_ih_n[(size_t)n * 8192 + t * 64 + k];
    }
    _Float16 hi = (_Float16)v;
    size_t base = (size_t)t * WN_T_HALF + nt * 2048 + kc * 1024 + u3;
    wnF[base]       = hi;
    wnF[base + 512] = (_Float16)(v - (float)hi);
  }
}

// ---------------------------------------------------------------------------
// Kernel 1: fused time-LSTM + note-GEMM partial sums.
// grid = NRT * tsplit blocks of 256 threads (4 waves, 32 rows each).
// __launch_bounds__(256, 2): 2 waves/EU min -> VGPR budget 256, no spills;
// LDS (77.8 KB) caps residency at 2 blocks/CU anyway.
// ---------------------------------------------------------------------------
__global__ __launch_bounds__(256, 2)
void k1_time_note(
    const float* __restrict__ x,
    const _Float16* __restrict__ wsel_hi, const _Float16* __restrict__ wsel_lo,
    const float* __restrict__ biasp, const _Float16* __restrict__ wnF,
    float* __restrict__ partials, int tchunk)
{
  __shared__ _Float16 wns[2][WN_T_HALF];             // 40960 B, dbuf
  __shared__ _Float16 tos_hi[ROWS_WG * TO_STRIDE];   // 18432 B
  __shared__ _Float16 tos_lo[ROWS_WG * TO_STRIDE];   // 18432 B -> 77824 total

  const int tid = threadIdx.x;
  const int l   = tid & 63;
  const int w   = tid >> 6;     // wave 0..3, owns rows [w*32, w*32+32)
  const int cl  = l & 15;
  const int kg  = l >> 4;       // 0..3

  const int rt   = blockIdx.x % NRT;
  const int ts   = blockIdx.x / NRT;
  const int row0 = rt * ROWS_WG;
  const int t0   = ts * tchunk;

  // W_ih_t fragments (prescaled): register-resident.
  half8 wth[12], wtl[12];
#pragma unroll
  for (int ct = 0; ct < 12; ++ct) {
    int off = (ct * 16 + cl) * 32 + kg * 8;
    wth[ct] = *(const half8*)(wsel_hi + off);
    wtl[ct] = *(const half8*)(wsel_lo + off);
  }
  float bias[3][4];
#pragma unroll
  for (int blk = 0; blk < 3; ++blk)
#pragma unroll
    for (int ctw = 0; ctw < 4; ++ctw)
      bias[blk][ctw] = biasp[blk * 64 + ctw * 16 + cl];

  f32x4 nacc[2][5];
#pragma unroll
  for (int mt = 0; mt < 2; ++mt)
#pragma unroll
    for (int nt = 0; nt < 5; ++nt)
      nacc[mt][nt] = (f32x4){0.f, 0.f, 0.f, 0.f};

  // per-lane x A-frag source: rows row0 + w*32 + mt*16 + cl, k = kg*8..kg*8+7
  const size_t xrow[2] = {
    (size_t)(row0 + w * 32 + 0  + cl) * 24 + kg * 8,
    (size_t)(row0 + w * 32 + 16 + cl) * 24 + kg * 8 };
  const bool xok = (kg < 3);

  // ---- prologue: load x[t0] to regs; wn[t0] -> wns[0] via global_load_lds ----
  float xcur[2][8];
#pragma unroll
  for (int mt = 0; mt < 2; ++mt) {
    f32x4 a = {0,0,0,0}, b = {0,0,0,0};
    if (xok) {
      const float* g = x + (size_t)t0 * NBROWS * 24 + xrow[mt];
      a = *(const f32x4*)g;
      b = *(const f32x4*)(g + 4);
    }
#pragma unroll
    for (int q = 0; q < 4; ++q) { xcur[mt][q] = a[q]; xcur[mt][4 + q] = b[q]; }
  }
  {
    const _Float16* src = wnF + (size_t)t0 * WN_T_HALF + w * 512 + l * 8;
    _Float16* dst = &wns[0][w * 512];    // wave-uniform; HW adds lane*16B
#pragma unroll
    for (int i = 0; i < 5; ++i)
      gload_lds16(src + i * 2048, dst + i * 2048);
  }
  __syncthreads();

  for (int tt = 0; tt < tchunk; ++tt) {
    const int rb = tt & 1, wb = rb ^ 1;
    int tg = t0 + tt + 1; if (tg > T_STEPS - 1) tg = T_STEPS - 1;

    // ---- 1. issue wn[t+1] -> wns[wb] (no VGPR round trip) ----
    {
      const _Float16* src = wnF + (size_t)tg * WN_T_HALF + w * 512 + l * 8;
      _Float16* dst = &wns[wb][w * 512];
#pragma unroll
      for (int i = 0; i < 5; ++i)
        gload_lds16(src + i * 2048, dst + i * 2048);
    }

    // ---- 2. split x[t] (prefetch regs) -> fp16 hi/lo A-frags ----
    half8 xah[2], xal[2];
#pragma unroll
    for (int mt = 0; mt < 2; ++mt) {
#pragma unroll
      for (int q = 0; q < 8; ++q) {
        _Float16 h = (_Float16)xcur[mt][q];
        xah[mt][q] = h;
        xal[mt][q] = (_Float16)(xcur[mt][q] - (float)h);
      }
    }

    // ---- 3. time MFMA + fused activations, per ctw (small live set) ----
    half4v pkh[2][4], pkl[2][4];
#pragma unroll
    for (int ctw = 0; ctw < 4; ++ctw) {
      f32x4 g[2][3];
#pragma unroll
      for (int mt = 0; mt < 2; ++mt)
#pragma unroll
        for (int blk = 0; blk < 3; ++blk) {
          int c = blk * 4 + ctw;
          float b = bias[blk][ctw];
          f32x4 a = (f32x4){b, b, b, b};
          a = mfma16(xah[mt], wth[c], a);   // hi*hi
          a = mfma16(xah[mt], wtl[c], a);   // hi*lo
          a = mfma16(xal[mt], wth[c], a);   // lo*hi
          g[mt][blk] = a;
        }
#pragma unroll
      for (int mt = 0; mt < 2; ++mt)
#pragma unroll
        for (int r = 0; r < 4; ++r) {
          float Ei = __builtin_amdgcn_exp2f(g[mt][0][r]);   // e^{-i}
          float Eg = __builtin_amdgcn_exp2f(g[mt][1][r]);   // e^{2g}
          float Eo = __builtin_amdgcn_exp2f(g[mt][2][r]);   // e^{-o}
          float d1 = (1.0f + Ei) * (1.0f + Eg);
          float cp = (SCALE_TANH * Eg - SCALE_TANH) * __builtin_amdgcn_rcpf(d1);
          float Ec = __builtin_amdgcn_exp2f(cp);            // e^{2c}
          float d2 = (1.0f + Eo) * (1.0f + Ec);
          float to = (Ec - 1.0f) * __builtin_amdgcn_rcpf(d2);
          _Float16 hh = (_Float16)to;
          pkh[mt][r][ctw] = hh;
          pkl[mt][r][ctw] = (_Float16)(to - (float)hh);
        }
    }

    // ---- 4. issue x[t+1] loads (covered by tos + note-MFMA) ----
    float xnxt[2][8];
#pragma unroll
    for (int mt = 0; mt < 2; ++mt) {
      f32x4 a = {0,0,0,0}, b = {0,0,0,0};
      if (xok) {
        const float* gp = x + (size_t)tg * NBROWS * 24 + xrow[mt];
        a = *(const f32x4*)gp;
        b = *(const f32x4*)(gp + 4);
      }
#pragma unroll
      for (int q = 0; q < 4; ++q) { xnxt[mt][q] = a[q]; xnxt[mt][4 + q] = b[q]; }
    }

    // ---- 5. tos write (wave-private rows) ----
#pragma unroll
    for (int mt = 0; mt < 2; ++mt)
#pragma unroll
      for (int r = 0; r < 4; ++r) {
        int row = w * 32 + mt * 16 + kg * 4 + r;
        *(half4v*)(tos_hi + row * TO_STRIDE + cl * 4) = pkh[mt][r];
        *(half4v*)(tos_lo + row * TO_STRIDE + cl * 4) = pkl[mt][r];
      }

    // ---- 6. note MFMA: nacc[32 x 80] += to[32 x 64] * WnT[64 x 80] ----
    half8 tah[2][2], tal[2][2];
#pragma unroll
    for (int mt = 0; mt < 2; ++mt)
#pragma unroll
      for (int kc = 0; kc < 2; ++kc) {
        int off = (w * 32 + mt * 16 + cl) * TO_STRIDE + kc * 32 + kg * 8;
        tah[mt][kc] = *(half8*)(tos_hi + off);
        tal[mt][kc] = *(half8*)(tos_lo + off);
      }
#pragma unroll
    for (int nt = 0; nt < 5; ++nt) {
#pragma unroll
      for (int kc = 0; kc < 2; ++kc) {
        const _Float16* bb = &wns[rb][nt * 2048 + kc * 1024 + l * 8];
        half8 bh = *(const half8*)(bb);         // plane hi
        half8 bl = *(const half8*)(bb + 512);   // plane lo
#pragma unroll
        for (int mt = 0; mt < 2; ++mt) {
          nacc[mt][nt] = mfma16(tah[mt][kc], bh, nacc[mt][nt]);
          nacc[mt][nt] = mfma16(tah[mt][kc], bl, nacc[mt][nt]);
          nacc[mt][nt] = mfma16(tal[mt][kc], bh, nacc[mt][nt]);
        }
      }
    }

    // ---- 7. barrier: drains wn[t+1] gload_lds (vmcnt) + syncs buffers ----
    __syncthreads();

    // ---- 8. rotate x prefetch ----
#pragma unroll
    for (int mt = 0; mt < 2; ++mt)
#pragma unroll
      for (int q = 0; q < 8; ++q) xcur[mt][q] = xnxt[mt][q];
  }

  // ---- write partial note-gate sums ----
  float* pbase = partials + (size_t)ts * NBROWS * NCOLS;
#pragma unroll
  for (int mt = 0; mt < 2; ++mt)
#pragma unroll
    for (int nt = 0; nt < 5; ++nt)
#pragma unroll
      for (int r = 0; r < 4; ++r) {
        int row = row0 + w * 32 + mt * 16 + kg * 4 + r;
        int col = nt * 16 + cl;
        pbase[(size_t)row * NCOLS + col] = nacc[mt][nt][r];
      }
}

// ---------------------------------------------------------------------------
// Kernel 2: reduce tsplit partials, note activations, threshold.
// ---------------------------------------------------------------------------
__global__ __launch_bounds__(256) void k2_note_out(
    const float* __restrict__ partials,
    const float* __restrict__ b_ih_n, const float* __restrict__ b_hh_n,
    float* __restrict__ out, int tsplit)
{
  int idx = blockIdx.x * 256 + threadIdx.x;
  if (idx >= NBROWS * 24) return;
  int row = idx / 24, jj = idx - row * 24;
  float gi = 0.f, gg = 0.f, go = 0.f;
  for (int p = 0; p < tsplit; ++p) {
    const float* pp = partials + ((size_t)p * NBROWS + row) * NCOLS;
    gi += pp[jj];
    gg += pp[24 + jj];
    go += pp[48 + jj];
  }
  gi += b_ih_n[jj]      + b_hh_n[jj];
  gg += b_ih_n[48 + jj] + b_hh_n[48 + jj];
  go += b_ih_n[72 + jj] + b_hh_n[72 + jj];
  float si = 1.f / (1.f + expf(-gi));
  float so = 1.f / (1.f + expf(-go));
  float v = so * tanhf(si * tanhf(gg));
  out[idx] = (v > 0.5f) ? 1.0f : 0.0f;
}

// ---------------------------------------------------------------------------
extern "C" void kernel_launch(void* const* d_in, const int* in_sizes, int n_in,
                              void* d_out, int out_size, void* d_ws, size_t ws_size,
                              hipStream_t stream)
{
  (void)in_sizes; (void)n_in; (void)out_size;
  const float* x      = (const float*)d_in[0];
  const float* W_ih_t = (const float*)d_in[1];
  const float* b_ih_t = (const float*)d_in[3];
  const float* b_hh_t = (const float*)d_in[4];
  const float* W_ih_n = (const float*)d_in[5];
  const float* b_ih_n = (const float*)d_in[7];
  const float* b_hh_n = (const float*)d_in[8];
  float* out = (float*)d_out;

  char* ws = (char*)d_ws;
  _Float16* wsel_hi = (_Float16*)(ws + 0);                   // 12288 B
  _Float16* wsel_lo = (_Float16*)(ws + 12288);               // 12288 B
  float*    biasp   = (float*)   (ws + 24576);               // 768 B
  _Float16* wnF     = (_Float16*)(ws + 32768);               // 128*10240*2 = 2621440 B
  float*    partials= (float*)   (ws + 4194304);             // tsplit*12288*80*4

  int tsplit = 8;
  while (tsplit > 1 &&
         4194304ull + (size_t)tsplit * NBROWS * NCOLS * 4 > ws_size)
    tsplit >>= 1;
  int tchunk = T_STEPS / tsplit;

  k0_prep<<<dim3(512), dim3(256), 0, stream>>>(
      W_ih_t, b_ih_t, b_hh_t, W_ih_n, wsel_hi, wsel_lo, biasp, wnF);

  k1_time_note<<<dim3(NRT * tsplit), dim3(256), 0, stream>>>(
      x, wsel_hi, wsel_lo, biasp, wnF, partials, tchunk);

  k2_note_out<<<dim3((NBROWS * 24 + 255) / 256), dim3(256), 0, stream>>>(
      partials, b_ih_n, b_hh_n, out, tsplit);
}

// Round 7
// 210.181 us; speedup vs baseline: 1.3328x; 1.0344x over previous
//
#include <hip/hip_runtime.h>

// ---------------------------------------------------------------------------
// MusicGenerationV2: two zero-state LSTM cells, fully fused MFMA pipeline.
//   time:  gates = x @ W_ih_t^T + b ; to = sig(o)*tanh(sig(i)*tanh(g))
//   note:  gates = note_in @ W_ih_n^T + b ; y = (sig(o)*tanh(sig(i)*tanh(g)) > 0.5)
// fp16 split-precision (hi+lo, 3 products) = fp32-level accuracy.
// Round 7: latency-coverage fixes.
//  - x(t+1) loads issued at the TOP of the iteration (HBM ~900cyc gets a full
//    iteration of compute cover; previously issued ~500cyc before the
//    barrier's vmcnt(0) drain -> every wave stalled there).
//  - tsplit 16: 1536 blocks = exactly 3 residency generations at 2 blk/CU
//    (768 was 1.5 -> half-empty tail generation).
//  - s_setprio(1) around the note-MFMA cluster (blocks are unsynced ->
//    scheduler can favor MFMA-phase waves).
// ---------------------------------------------------------------------------

typedef _Float16 half8  __attribute__((ext_vector_type(8)));
typedef _Float16 half4v __attribute__((ext_vector_type(4)));
typedef float    f32x4  __attribute__((ext_vector_type(4)));

#define T_STEPS 128
#define NBROWS  12288      // 12 notes * 1024 batch
#define ROWS_WG 128        // rows per workgroup (4 waves x 32 rows)
#define NRT     96         // NBROWS / ROWS_WG
#define NCOLS   80         // note gate cols kept: i(24) g(24) o(24) pad(8)
#define TO_STRIDE 72       // to tile [128][72] halves
#define WN_T_HALF 10240    // per-t frag-ordered wn halves (5nt*2kc*2p*512)

__device__ inline f32x4 mfma16(half8 a, half8 b, f32x4 c) {
  return __builtin_amdgcn_mfma_f32_16x16x32_f16(a, b, c, 0, 0, 0);
}

__device__ inline void gload_lds16(const _Float16* gsrc, _Float16* ldst) {
  __builtin_amdgcn_global_load_lds(
      (const __attribute__((address_space(1))) void*)gsrc,
      (__attribute__((address_space(3))) void*)ldst, 16, 0, 0);
}

#define SCALE_SIG  -1.4426950408889634f   // -log2(e)
#define SCALE_TANH  2.8853900817779268f   // 2*log2(e)

// ---------------------------------------------------------------------------
// Kernel 0: prescale+split time weights; note weights -> fragment order.
// wsel[c][k]: c=blk*64+ctw*16+cl maps gate col h=cl*4+ctw of gate blk {i,g,o}.
// wnF[t*10240 + nt*2048 + kc*1024 + p*512 + l*8 + j]:
//   value = plane_p( Wsel[rcol=nt*16+cl][k=kc*32+kg*8+j] ), l=kg*16+cl,
//   rcol<24 -> W_ih_n row rcol; 24<=rcol<72 -> row rcol+24 (skip f); else 0.
// ---------------------------------------------------------------------------
__global__ __launch_bounds__(256) void k0_prep(
    const float* __restrict__ W_ih_t, const float* __restrict__ b_ih_t,
    const float* __restrict__ b_hh_t, const float* __restrict__ W_ih_n,
    _Float16* __restrict__ wsel_hi, _Float16* __restrict__ wsel_lo,
    float* __restrict__ biasp, _Float16* __restrict__ wnF)
{
  int id = blockIdx.x * 256 + threadIdx.x;
  if (id < 192 * 32) {
    int c = id >> 5, k = id & 31;
    int blk = c >> 6, ci = c & 63;
    int cl = ci & 15, ctw = ci >> 4;
    int h = cl * 4 + ctw;
    int grow = (blk == 0 ? 0 : (blk == 1 ? 128 : 192)) + h;  // i,g,o rows
    float scale = (blk == 1) ? SCALE_TANH : SCALE_SIG;
    float v = (k < 24) ? W_ih_t[grow * 24 + k] * scale : 0.0f;
    _Float16 hi = (_Float16)v;
    wsel_hi[id] = hi;
    wsel_lo[id] = (_Float16)(v - (float)hi);
    if (k == 0) biasp[c] = (b_ih_t[grow] + b_hh_t[grow]) * scale;
  }
  // e indexes (t, nt, kc, l, j); hi at p=0, lo at p=1 (+512 halves)
  for (int e = id; e < T_STEPS * 5120; e += gridDim.x * 256) {
    int t = e / 5120, u = e - t * 5120;
    int nt = u >> 10, u2 = u & 1023;
    int kc = u2 >> 9, u3 = u2 & 511;
    int l = u3 >> 3, j = u3 & 7;
    int cl = l & 15, kg = l >> 4;
    int rcol = nt * 16 + cl;
    int k = kc * 32 + kg * 8 + j;
    float v = 0.0f;
    if (rcol < 72) {
      int n = (rcol < 24) ? rcol : rcol + 24;   // skip f-gate rows 24..47
      v = W_ih_n[(size_t)n * 8192 + t * 64 + k];
    }
    _Float16 hi = (_Float16)v;
    size_t base = (size_t)t * WN_T_HALF + nt * 2048 + kc * 1024 + u3;
    wnF[base]       = hi;
    wnF[base + 512] = (_Float16)(v - (float)hi);
  }
}

// ---------------------------------------------------------------------------
// Kernel 1: fused time-LSTM + note-GEMM partial sums.
// grid = NRT * tsplit blocks of 256 threads (4 waves, 32 rows each).
// ---------------------------------------------------------------------------
__global__ __launch_bounds__(256, 2)
void k1_time_note(
    const float* __restrict__ x,
    const _Float16* __restrict__ wsel_hi, const _Float16* __restrict__ wsel_lo,
    const float* __restrict__ biasp, const _Float16* __restrict__ wnF,
    float* __restrict__ partials, int tchunk)
{
  __shared__ _Float16 wns[2][WN_T_HALF];             // 40960 B, dbuf
  __shared__ _Float16 tos_hi[ROWS_WG * TO_STRIDE];   // 18432 B
  __shared__ _Float16 tos_lo[ROWS_WG * TO_STRIDE];   // 18432 B -> 77824 total

  const int tid = threadIdx.x;
  const int l   = tid & 63;
  const int w   = tid >> 6;     // wave 0..3, owns rows [w*32, w*32+32)
  const int cl  = l & 15;
  const int kg  = l >> 4;       // 0..3

  const int rt   = blockIdx.x % NRT;
  const int ts   = blockIdx.x / NRT;
  const int row0 = rt * ROWS_WG;
  const int t0   = ts * tchunk;

  // W_ih_t fragments (prescaled): register-resident.
  half8 wth[12], wtl[12];
#pragma unroll
  for (int ct = 0; ct < 12; ++ct) {
    int off = (ct * 16 + cl) * 32 + kg * 8;
    wth[ct] = *(const half8*)(wsel_hi + off);
    wtl[ct] = *(const half8*)(wsel_lo + off);
  }
  float bias[3][4];
#pragma unroll
  for (int blk = 0; blk < 3; ++blk)
#pragma unroll
    for (int ctw = 0; ctw < 4; ++ctw)
      bias[blk][ctw] = biasp[blk * 64 + ctw * 16 + cl];

  f32x4 nacc[2][5];
#pragma unroll
  for (int mt = 0; mt < 2; ++mt)
#pragma unroll
    for (int nt = 0; nt < 5; ++nt)
      nacc[mt][nt] = (f32x4){0.f, 0.f, 0.f, 0.f};

  // per-lane x A-frag source: rows row0 + w*32 + mt*16 + cl, k = kg*8..kg*8+7
  const size_t xrow[2] = {
    (size_t)(row0 + w * 32 + 0  + cl) * 24 + kg * 8,
    (size_t)(row0 + w * 32 + 16 + cl) * 24 + kg * 8 };
  const bool xok = (kg < 3);

  // ---- prologue: load x[t0] to regs; wn[t0] -> wns[0] via global_load_lds ----
  float xcur[2][8];
#pragma unroll
  for (int mt = 0; mt < 2; ++mt) {
    f32x4 a = {0,0,0,0}, b = {0,0,0,0};
    if (xok) {
      const float* g = x + (size_t)t0 * NBROWS * 24 + xrow[mt];
      a = *(const f32x4*)g;
      b = *(const f32x4*)(g + 4);
    }
#pragma unroll
    for (int q = 0; q < 4; ++q) { xcur[mt][q] = a[q]; xcur[mt][4 + q] = b[q]; }
  }
  {
    const _Float16* src = wnF + (size_t)t0 * WN_T_HALF + w * 512 + l * 8;
    _Float16* dst = &wns[0][w * 512];    // wave-uniform; HW adds lane*16B
#pragma unroll
    for (int i = 0; i < 5; ++i)
      gload_lds16(src + i * 2048, dst + i * 2048);
  }
  __syncthreads();

  for (int tt = 0; tt < tchunk; ++tt) {
    const int rb = tt & 1, wb = rb ^ 1;
    int tg = t0 + tt + 1; if (tg > T_STEPS - 1) tg = T_STEPS - 1;

    // ---- 1. issue x[t+1] loads FIRST (HBM latency ~900cyc; now covered by
    //         the whole iteration instead of ~500cyc) ----
    float xnxt[2][8];
#pragma unroll
    for (int mt = 0; mt < 2; ++mt) {
      f32x4 a = {0,0,0,0}, b = {0,0,0,0};
      if (xok) {
        const float* gp = x + (size_t)tg * NBROWS * 24 + xrow[mt];
        a = *(const f32x4*)gp;
        b = *(const f32x4*)(gp + 4);
      }
#pragma unroll
      for (int q = 0; q < 4; ++q) { xnxt[mt][q] = a[q]; xnxt[mt][4 + q] = b[q]; }
    }

    // ---- 2. issue wn[t+1] -> wns[wb] (L2-resident, short latency) ----
    {
      const _Float16* src = wnF + (size_t)tg * WN_T_HALF + w * 512 + l * 8;
      _Float16* dst = &wns[wb][w * 512];
#pragma unroll
      for (int i = 0; i < 5; ++i)
        gload_lds16(src + i * 2048, dst + i * 2048);
    }

    // ---- 3. split x[t] (prefetch regs) -> fp16 hi/lo A-frags ----
    half8 xah[2], xal[2];
#pragma unroll
    for (int mt = 0; mt < 2; ++mt) {
#pragma unroll
      for (int q = 0; q < 8; ++q) {
        _Float16 h = (_Float16)xcur[mt][q];
        xah[mt][q] = h;
        xal[mt][q] = (_Float16)(xcur[mt][q] - (float)h);
      }
    }

    // ---- 4. time MFMA + fused activations, per ctw (small live set) ----
    half4v pkh[2][4], pkl[2][4];
#pragma unroll
    for (int ctw = 0; ctw < 4; ++ctw) {
      f32x4 g[2][3];
#pragma unroll
      for (int mt = 0; mt < 2; ++mt)
#pragma unroll
        for (int blk = 0; blk < 3; ++blk) {
          int c = blk * 4 + ctw;
          float b = bias[blk][ctw];
          f32x4 a = (f32x4){b, b, b, b};
          a = mfma16(xah[mt], wth[c], a);   // hi*hi
          a = mfma16(xah[mt], wtl[c], a);   // hi*lo
          a = mfma16(xal[mt], wth[c], a);   // lo*hi
          g[mt][blk] = a;
        }
#pragma unroll
      for (int mt = 0; mt < 2; ++mt)
#pragma unroll
        for (int r = 0; r < 4; ++r) {
          float Ei = __builtin_amdgcn_exp2f(g[mt][0][r]);   // e^{-i}
          float Eg = __builtin_amdgcn_exp2f(g[mt][1][r]);   // e^{2g}
          float Eo = __builtin_amdgcn_exp2f(g[mt][2][r]);   // e^{-o}
          float d1 = (1.0f + Ei) * (1.0f + Eg);
          float cp = (SCALE_TANH * Eg - SCALE_TANH) * __builtin_amdgcn_rcpf(d1);
          float Ec = __builtin_amdgcn_exp2f(cp);            // e^{2c}
          float d2 = (1.0f + Eo) * (1.0f + Ec);
          float to = (Ec - 1.0f) * __builtin_amdgcn_rcpf(d2);
          _Float16 hh = (_Float16)to;
          pkh[mt][r][ctw] = hh;
          pkl[mt][r][ctw] = (_Float16)(to - (float)hh);
        }
    }

    // ---- 5. tos write (wave-private rows) ----
#pragma unroll
    for (int mt = 0; mt < 2; ++mt)
#pragma unroll
      for (int r = 0; r < 4; ++r) {
        int row = w * 32 + mt * 16 + kg * 4 + r;
        *(half4v*)(tos_hi + row * TO_STRIDE + cl * 4) = pkh[mt][r];
        *(half4v*)(tos_lo + row * TO_STRIDE + cl * 4) = pkl[mt][r];
      }

    // ---- 6. note MFMA: nacc[32 x 80] += to[32 x 64] * WnT[64 x 80] ----
    half8 tah[2][2], tal[2][2];
#pragma unroll
    for (int mt = 0; mt < 2; ++mt)
#pragma unroll
      for (int kc = 0; kc < 2; ++kc) {
        int off = (w * 32 + mt * 16 + cl) * TO_STRIDE + kc * 32 + kg * 8;
        tah[mt][kc] = *(half8*)(tos_hi + off);
        tal[mt][kc] = *(half8*)(tos_lo + off);
      }
    __builtin_amdgcn_s_setprio(1);
#pragma unroll
    for (int nt = 0; nt < 5; ++nt) {
#pragma unroll
      for (int kc = 0; kc < 2; ++kc) {
        const _Float16* bb = &wns[rb][nt * 2048 + kc * 1024 + l * 8];
        half8 bh = *(const half8*)(bb);         // plane hi
        half8 bl = *(const half8*)(bb + 512);   // plane lo
#pragma unroll
        for (int mt = 0; mt < 2; ++mt) {
          nacc[mt][nt] = mfma16(tah[mt][kc], bh, nacc[mt][nt]);
          nacc[mt][nt] = mfma16(tah[mt][kc], bl, nacc[mt][nt]);
          nacc[mt][nt] = mfma16(tal[mt][kc], bh, nacc[mt][nt]);
        }
      }
    }
    __builtin_amdgcn_s_setprio(0);

    // ---- 7. barrier: drains wn[t+1] gload_lds + x[t+1] (both long done) ----
    __syncthreads();

    // ---- 8. rotate x prefetch ----
#pragma unroll
    for (int mt = 0; mt < 2; ++mt)
#pragma unroll
      for (int q = 0; q < 8; ++q) xcur[mt][q] = xnxt[mt][q];
  }

  // ---- write partial note-gate sums ----
  float* pbase = partials + (size_t)ts * NBROWS * NCOLS;
#pragma unroll
  for (int mt = 0; mt < 2; ++mt)
#pragma unroll
    for (int nt = 0; nt < 5; ++nt)
#pragma unroll
      for (int r = 0; r < 4; ++r) {
        int row = row0 + w * 32 + mt * 16 + kg * 4 + r;
        int col = nt * 16 + cl;
        pbase[(size_t)row * NCOLS + col] = nacc[mt][nt][r];
      }
}

// ---------------------------------------------------------------------------
// Kernel 2: reduce tsplit partials, note activations, threshold.
// ---------------------------------------------------------------------------
__global__ __launch_bounds__(256) void k2_note_out(
    const float* __restrict__ partials,
    const float* __restrict__ b_ih_n, const float* __restrict__ b_hh_n,
    float* __restrict__ out, int tsplit)
{
  int idx = blockIdx.x * 256 + threadIdx.x;
  if (idx >= NBROWS * 24) return;
  int row = idx / 24, jj = idx - row * 24;
  float gi = 0.f, gg = 0.f, go = 0.f;
  for (int p = 0; p < tsplit; ++p) {
    const float* pp = partials + ((size_t)p * NBROWS + row) * NCOLS;
    gi += pp[jj];
    gg += pp[24 + jj];
    go += pp[48 + jj];
  }
  gi += b_ih_n[jj]      + b_hh_n[jj];
  gg += b_ih_n[48 + jj] + b_hh_n[48 + jj];
  go += b_ih_n[72 + jj] + b_hh_n[72 + jj];
  float si = 1.f / (1.f + expf(-gi));
  float so = 1.f / (1.f + expf(-go));
  float v = so * tanhf(si * tanhf(gg));
  out[idx] = (v > 0.5f) ? 1.0f : 0.0f;
}

// ---------------------------------------------------------------------------
extern "C" void kernel_launch(void* const* d_in, const int* in_sizes, int n_in,
                              void* d_out, int out_size, void* d_ws, size_t ws_size,
                              hipStream_t stream)
{
  (void)in_sizes; (void)n_in; (void)out_size;
  const float* x      = (const float*)d_in[0];
  const float* W_ih_t = (const float*)d_in[1];
  const float* b_ih_t = (const float*)d_in[3];
  const float* b_hh_t = (const float*)d_in[4];
  const float* W_ih_n = (const float*)d_in[5];
  const float* b_ih_n = (const float*)d_in[7];
  const float* b_hh_n = (const float*)d_in[8];
  float* out = (float*)d_out;

  char* ws = (char*)d_ws;
  _Float16* wsel_hi = (_Float16*)(ws + 0);                   // 12288 B
  _Float16* wsel_lo = (_Float16*)(ws + 12288);               // 12288 B
  float*    biasp   = (float*)   (ws + 24576);               // 768 B
  _Float16* wnF     = (_Float16*)(ws + 32768);               // 128*10240*2 = 2621440 B
  float*    partials= (float*)   (ws + 4194304);             // tsplit*12288*80*4

  // tsplit=16 -> 1536 blocks = exactly 3 residency generations (2 blk/CU).
  int tsplit = 16;
  while (tsplit > 1 &&
         4194304ull + (size_t)tsplit * NBROWS * NCOLS * 4 > ws_size)
    tsplit >>= 1;
  int tchunk = T_STEPS / tsplit;

  k0_prep<<<dim3(512), dim3(256), 0, stream>>>(
      W_ih_t, b_ih_t, b_hh_t, W_ih_n, wsel_hi, wsel_lo, biasp, wnF);

  k1_time_note<<<dim3(NRT * tsplit), dim3(256), 0, stream>>>(
      x, wsel_hi, wsel_lo, biasp, wnF, partials, tchunk);

  k2_note_out<<<dim3((NBROWS * 24 + 255) / 256), dim3(256), 0, stream>>>(
      partials, b_ih_n, b_hh_n, out, tsplit);
}